// Round 1
// baseline (526.417 us; speedup 1.0000x reference)
//
#include <hip/hip_runtime.h>
#include <hip/hip_bf16.h>
#include <cstdint>

// SNN: Poisson encode (noise < x) -> [T=32] { h = sp@W1^T; v+=h; spike=(v>1); v-=spike; logits += spike@W2^T }
// B=8192, T=32, D_IN=784 (pad K to 800 = 25x32), D_H=100 (pad N to 128 = 8x16), D_OUT=10.
//
// Decomposition:
//  K0 prep_w1 : W1 -> MFMA-B-fragment-layout bf16 hi/lo pairs in ws (hi+lo splits f32 to ~1e-7 rel).
//  K1 snn_gemm: H[t,b,h] for ALL t (M = 32*8192 = 262144 rows) via mfma_f32_16x16x32_bf16,
//               spikes generated in-register from noise<x (exact f32 compare). H -> ws (f32).
//  K2 snn_scan: per (b,h): v+=H[t]; s=(v-1>0); v-=s; cnt+=s  (exact IF dynamics),
//               then logits[b,o] = sum_h cnt[b,h]*W2[o,h]  (W2 is t-invariant => one tiny GEMM).

typedef __attribute__((ext_vector_type(8))) short bf16x8;
typedef __attribute__((ext_vector_type(4))) float f32x4;

#define D_IN 784
#define NB 8192
#define NT 32
#define KT 25   // K tiles of 32 (800 padded)
#define NTL 8   // N tiles of 16 (128 padded)

// ---------------- K0: pack W1 into fragment-ready bf16 hi/lo ----------------
// Fragment f = (kt*8 + nt), stored as [f][hi(512 ushorts) | lo(512 ushorts)].
// B-slot(lane l, elem j): n = nt*16 + (l&15), i = kt*32 + (l>>4)*8 + j.
__global__ void prep_w1(const float* __restrict__ W1, unsigned short* __restrict__ wf) {
    int idx = blockIdx.x * 256 + threadIdx.x;           // 25*8*64 = 12800
    if (idx >= KT * NTL * 64) return;
    int l  = idx & 63;
    int nt = (idx >> 6) & 7;
    int kt = idx >> 9;
    int n  = nt * 16 + (l & 15);
    int i0 = kt * 32 + (l >> 4) * 8;
    size_t fbase = (size_t)(kt * 8 + nt) * 1024;        // ushort offset of hi block
    #pragma unroll
    for (int j = 0; j < 8; ++j) {
        int i = i0 + j;
        float w = (n < 100 && i < D_IN) ? W1[n * D_IN + i] : 0.f;
        // bf16 RNE
        uint32_t ub = __float_as_uint(w);
        uint32_t rh = ub + 0x7FFFu + ((ub >> 16) & 1u);
        unsigned short h = (unsigned short)(rh >> 16);
        float hf = __uint_as_float(((uint32_t)h) << 16);
        float resid = w - hf;                            // exact (Sterbenz)
        uint32_t ul = __float_as_uint(resid);
        uint32_t rl = ul + 0x7FFFu + ((ul >> 16) & 1u);
        unsigned short lo = (unsigned short)(rl >> 16);
        wf[fbase + l * 8 + j]       = h;
        wf[fbase + 512 + l * 8 + j] = lo;
    }
}

// ---------------- K1: H = spikes @ W1^T for all (t,b) ----------------
// Block: 256 thr = 4 waves as 2(M)x2(N). Block tile = 128 M-rows x 128 hidden.
// Wave: 4 M-tiles x 4 N-tiles. M flattened = t*8192 + b (blocks never straddle t).
__global__ __launch_bounds__(256) void snn_gemm(const float* __restrict__ x,
                                                const float* __restrict__ noise,
                                                const unsigned short* __restrict__ wf,
                                                float* __restrict__ H) {
    const int tid   = threadIdx.x;
    const int lane  = tid & 63;
    const int wave  = tid >> 6;
    const int Mhalf = wave >> 1;
    const int Nhalf = wave & 1;
    const int M0    = blockIdx.x * 128;
    const int t     = M0 >> 13;                         // /8192
    const int brow0 = (M0 & (NB - 1)) + Mhalf * 64 + (lane & 15);
    const int iLane = (lane >> 4) * 8;
    const float* nb = noise + (size_t)t * ((size_t)NB * D_IN);

    f32x4 acc[4][4];
    #pragma unroll
    for (int i = 0; i < 4; ++i)
        #pragma unroll
        for (int j = 0; j < 4; ++j) acc[i][j] = (f32x4){0.f, 0.f, 0.f, 0.f};

    for (int kt = 0; kt < KT; ++kt) {
        const int i0 = kt * 32 + iLane;
        const bool valid = (i0 < D_IN);                 // tail tile: i>=784 -> spike 0 (W1 pad 0 too)
        bf16x8 afr[4];
        #pragma unroll
        for (int mt = 0; mt < 4; ++mt) {
            const int b = brow0 + mt * 16;
            union { uint32_t u[4]; bf16x8 v; } pk;
            pk.u[0] = pk.u[1] = pk.u[2] = pk.u[3] = 0u;
            if (valid) {
                const size_t ro = (size_t)b * D_IN + i0;
                const float4 n0 = *reinterpret_cast<const float4*>(nb + ro);
                const float4 n1 = *reinterpret_cast<const float4*>(nb + ro + 4);
                const float4 x0 = *reinterpret_cast<const float4*>(x + ro);
                const float4 x1 = *reinterpret_cast<const float4*>(x + ro + 4);
                pk.u[0] = (n0.x < x0.x ? 0x3F80u : 0u) | (n0.y < x0.y ? 0x3F800000u : 0u);
                pk.u[1] = (n0.z < x0.z ? 0x3F80u : 0u) | (n0.w < x0.w ? 0x3F800000u : 0u);
                pk.u[2] = (n1.x < x1.x ? 0x3F80u : 0u) | (n1.y < x1.y ? 0x3F800000u : 0u);
                pk.u[3] = (n1.z < x1.z ? 0x3F80u : 0u) | (n1.w < x1.w ? 0x3F800000u : 0u);
            }
            afr[mt] = pk.v;
        }
        #pragma unroll
        for (int nt = 0; nt < 4; ++nt) {
            const size_t fo = (size_t)(kt * 8 + Nhalf * 4 + nt) * 1024 + lane * 8;
            const bf16x8 bhi = *reinterpret_cast<const bf16x8*>(wf + fo);
            const bf16x8 blo = *reinterpret_cast<const bf16x8*>(wf + fo + 512);
            #pragma unroll
            for (int mt = 0; mt < 4; ++mt) {
                acc[mt][nt] = __builtin_amdgcn_mfma_f32_16x16x32_bf16(afr[mt], bhi, acc[mt][nt], 0, 0, 0);
                acc[mt][nt] = __builtin_amdgcn_mfma_f32_16x16x32_bf16(afr[mt], blo, acc[mt][nt], 0, 0, 0);
            }
        }
    }
    // C/D layout (m89-verified): col = lane&15, row = (lane>>4)*4 + reg
    const int colBase   = Nhalf * 64 + (lane & 15);
    const int rowInTile = (lane >> 4) * 4;
    #pragma unroll
    for (int mt = 0; mt < 4; ++mt) {
        const size_t rg = (size_t)M0 + Mhalf * 64 + mt * 16 + rowInTile;
        #pragma unroll
        for (int nt = 0; nt < 4; ++nt) {
            const int col = colBase + nt * 16;
            #pragma unroll
            for (int r = 0; r < 4; ++r)
                H[(rg + r) * 128 + col] = acc[mt][nt][r];
        }
    }
}

// ---------------- K2: IF scan over t + logits = cnt @ W2^T ----------------
__global__ __launch_bounds__(256) void snn_scan(const float* __restrict__ H,
                                                const float* __restrict__ W2,
                                                float* __restrict__ out) {
    __shared__ float cbuf[2][128];
    __shared__ float w2s[1000];
    const int tid = threadIdx.x;
    const int r = tid >> 7, h = tid & 127;
    const size_t b = (size_t)blockIdx.x * 2 + r;
    for (int i = tid; i < 1000; i += 256) w2s[i] = W2[i];

    float hv[32];
    #pragma unroll
    for (int t = 0; t < 32; ++t) hv[t] = H[((size_t)t * NB + b) * 128 + h];

    float v = 0.f, cnt = 0.f;
    #pragma unroll
    for (int t = 0; t < 32; ++t) {
        v += hv[t];
        float s = (v - 1.0f > 0.0f) ? 1.0f : 0.0f;      // exact reference semantics
        v -= s;
        cnt += s;
    }
    cbuf[r][h] = cnt;
    __syncthreads();
    if (tid < 20) {
        const int rr = tid / 10, o = tid % 10;
        float s = 0.f;
        for (int hh = 0; hh < 100; ++hh) s += cbuf[rr][hh] * w2s[o * 100 + hh];
        out[((size_t)blockIdx.x * 2 + rr) * 10 + o] = s;
    }
}

extern "C" void kernel_launch(void* const* d_in, const int* in_sizes, int n_in,
                              void* d_out, int out_size, void* d_ws, size_t ws_size,
                              hipStream_t stream) {
    const float* x     = (const float*)d_in[0];   // [8192,784]
    const float* noise = (const float*)d_in[1];   // [32,8192,784]
    const float* W1    = (const float*)d_in[2];   // [100,784]
    const float* W2    = (const float*)d_in[3];   // [10,100]
    float* out = (float*)d_out;                   // [8192,10]

    unsigned short* wf = (unsigned short*)d_ws;                    // 409.6 KB W1 frags
    float* H = (float*)((char*)d_ws + (1u << 20));                 // 128 MB H buffer

    prep_w1<<<50, 256, 0, stream>>>(W1, wf);
    snn_gemm<<<2048, 256, 0, stream>>>(x, noise, wf, H);
    snn_scan<<<4096, 256, 0, stream>>>(H, W2, out);
}

// Round 2
// 360.696 us; speedup vs baseline: 1.4594x; 1.4594x over previous
//
#include <hip/hip_runtime.h>
#include <hip/hip_bf16.h>
#include <cstdint>

// SNN: Poisson encode (noise < x) -> [T=32] { h = sp@W1^T; v+=h; spike=(v>1); v-=spike; logits += spike@W2^T }
// B=8192, T=32, D_IN=784 (pad K to 800 = 25x32), D_H=100 (pad N to 128), D_OUT=10.
//
//  K0 prep_w1 : W1 -> MFMA-B-fragment-layout bf16 hi/lo pairs in ws.
//  K1 snn_gemm: H[t,b,h] via mfma_f32_16x16x32_bf16. v2: noise+x LDS-staged with
//               coalesced global_load_lds (pre-swizzled source, m173 pattern);
//               spikes generated in-register from LDS tiles (exact f32 compare).
//  K2 snn_scan: IF scan over t, then logits = spikecount @ W2^T (W2 t-invariant).

typedef __attribute__((ext_vector_type(8))) short bf16x8;
typedef __attribute__((ext_vector_type(4))) float f32x4;

#define D_IN 784
#define NB 8192
#define KT 25   // K tiles of 32 (800 padded)
#define NTL 8   // N tiles of 16 (128 padded)

__device__ __forceinline__ void gload_lds16(const float* g, float* l) {
    __builtin_amdgcn_global_load_lds((const __attribute__((address_space(1))) void*)g,
                                     (__attribute__((address_space(3))) void*)l, 16, 0, 0);
}

// ---------------- K0: pack W1 into fragment-ready bf16 hi/lo ----------------
// Fragment f = (kt*8 + nt), stored as [f][hi(512 ushorts) | lo(512 ushorts)].
// B-slot(lane l, elem j): n = nt*16 + (l&15), i = kt*32 + (l>>4)*8 + j.
__global__ void prep_w1(const float* __restrict__ W1, unsigned short* __restrict__ wf) {
    int idx = blockIdx.x * 256 + threadIdx.x;           // 25*8*64 = 12800
    if (idx >= KT * NTL * 64) return;
    int l  = idx & 63;
    int nt = (idx >> 6) & 7;
    int kt = idx >> 9;
    int n  = nt * 16 + (l & 15);
    int i0 = kt * 32 + (l >> 4) * 8;
    size_t fbase = (size_t)(kt * 8 + nt) * 1024;
    #pragma unroll
    for (int j = 0; j < 8; ++j) {
        int i = i0 + j;
        float w = (n < 100 && i < D_IN) ? W1[n * D_IN + i] : 0.f;
        uint32_t ub = __float_as_uint(w);
        uint32_t rh = ub + 0x7FFFu + ((ub >> 16) & 1u);
        unsigned short h = (unsigned short)(rh >> 16);
        float hf = __uint_as_float(((uint32_t)h) << 16);
        float resid = w - hf;
        uint32_t ul = __float_as_uint(resid);
        uint32_t rl = ul + 0x7FFFu + ((ul >> 16) & 1u);
        unsigned short lo = (unsigned short)(rl >> 16);
        wf[fbase + l * 8 + j]       = h;
        wf[fbase + 512 + l * 8 + j] = lo;
    }
}

// ---------------- K1: H = spikes @ W1^T for all (t,b) ----------------
// Block: 256 thr = 4 waves as 2(M)x2(N). Block tile = 128 rows x 128 hidden.
// Per kt: stage noise[128x32] + x[128x32] (16KB each) into LDS, coalesced.
// Granule = 16B (4 floats). Tile = 128 rows x 8 granules = 1024 slots.
// Swizzle: slot(r,c) = r*8 + (c ^ (r&7))  -> ds_read_b128 conflict <= 2-way.
// global_load_lds writes slot = base + lane linearly, so the SOURCE address is
// pre-swizzled (slot s holds global granule c = (s&7)^(r&7)).
__global__ __launch_bounds__(256) void snn_gemm(const float* __restrict__ x,
                                                const float* __restrict__ noise,
                                                const unsigned short* __restrict__ wf,
                                                float* __restrict__ H) {
    __shared__ __align__(16) float sN[4096];   // 16KB
    __shared__ __align__(16) float sX[4096];   // 16KB
    const int tid   = threadIdx.x;
    const int lane  = tid & 63;
    const int wave  = tid >> 6;
    const int Mhalf = wave >> 1;
    const int Nhalf = wave & 1;
    const int M0    = blockIdx.x * 128;
    const int t     = M0 >> 13;
    const int b0    = M0 & (NB - 1);
    const float* nb = noise + (size_t)t * ((size_t)NB * D_IN);

    // staging map: thread stages slots s = i*256 + tid, i=0..3
    int sRow[4], sCg[4];
    #pragma unroll
    for (int i = 0; i < 4; ++i) {
        int s = i * 256 + tid;
        sRow[i] = s >> 3;
        sCg[i]  = (s & 7) ^ (sRow[i] & 7);
    }
    // fragment-read slots: row = Mhalf*64 + mt*16 + (lane&15), granules c0, c0+1
    const int c0 = (lane >> 4) * 2;
    int fSlot[4][2];
    #pragma unroll
    for (int mt = 0; mt < 4; ++mt) {
        int row = Mhalf * 64 + mt * 16 + (lane & 15);
        fSlot[mt][0] = row * 8 + (c0 ^ (row & 7));
        fSlot[mt][1] = row * 8 + ((c0 + 1) ^ (row & 7));
    }

    f32x4 acc[4][4];
    #pragma unroll
    for (int i = 0; i < 4; ++i)
        #pragma unroll
        for (int j = 0; j < 4; ++j) acc[i][j] = (f32x4){0.f, 0.f, 0.f, 0.f};

    #pragma unroll 1
    for (int kt = 0; kt < KT; ++kt) {
        __syncthreads();                                 // LDS reads of kt-1 done
        #pragma unroll
        for (int i = 0; i < 4; ++i) {
            int colf = kt * 32 + sCg[i] * 4;
            if (kt == KT - 1 && sCg[i] >= 4) colf = (KT - 1) * 32;  // clamp: contents hit W1 pad=0
            const size_t ro = (size_t)(b0 + sRow[i]) * D_IN + colf;
            const int base = i * 256 + wave * 64;        // wave-uniform; HW adds lane*16
            gload_lds16(nb + ro, &sN[base * 4]);
            gload_lds16(x + ro,  &sX[base * 4]);
        }
        __syncthreads();                                 // staged data visible

        bf16x8 afr[4];
        #pragma unroll
        for (int mt = 0; mt < 4; ++mt) {
            const float4 n0 = *reinterpret_cast<const float4*>(&sN[fSlot[mt][0] * 4]);
            const float4 n1 = *reinterpret_cast<const float4*>(&sN[fSlot[mt][1] * 4]);
            const float4 x0 = *reinterpret_cast<const float4*>(&sX[fSlot[mt][0] * 4]);
            const float4 x1 = *reinterpret_cast<const float4*>(&sX[fSlot[mt][1] * 4]);
            union { uint32_t u[4]; bf16x8 v; } pk;
            pk.u[0] = (n0.x < x0.x ? 0x3F80u : 0u) | (n0.y < x0.y ? 0x3F800000u : 0u);
            pk.u[1] = (n0.z < x0.z ? 0x3F80u : 0u) | (n0.w < x0.w ? 0x3F800000u : 0u);
            pk.u[2] = (n1.x < x1.x ? 0x3F80u : 0u) | (n1.y < x1.y ? 0x3F800000u : 0u);
            pk.u[3] = (n1.z < x1.z ? 0x3F80u : 0u) | (n1.w < x1.w ? 0x3F800000u : 0u);
            afr[mt] = pk.v;
        }
        #pragma unroll
        for (int nt = 0; nt < 4; ++nt) {
            const size_t fo = (size_t)(kt * 8 + Nhalf * 4 + nt) * 1024 + lane * 8;
            const bf16x8 bhi = *reinterpret_cast<const bf16x8*>(wf + fo);
            const bf16x8 blo = *reinterpret_cast<const bf16x8*>(wf + fo + 512);
            #pragma unroll
            for (int mt = 0; mt < 4; ++mt) {
                acc[mt][nt] = __builtin_amdgcn_mfma_f32_16x16x32_bf16(afr[mt], bhi, acc[mt][nt], 0, 0, 0);
                acc[mt][nt] = __builtin_amdgcn_mfma_f32_16x16x32_bf16(afr[mt], blo, acc[mt][nt], 0, 0, 0);
            }
        }
    }
    // C/D layout: col = lane&15, row = (lane>>4)*4 + reg
    const int colBase   = Nhalf * 64 + (lane & 15);
    const int rowInTile = (lane >> 4) * 4;
    #pragma unroll
    for (int mt = 0; mt < 4; ++mt) {
        const size_t rg = (size_t)M0 + Mhalf * 64 + mt * 16 + rowInTile;
        #pragma unroll
        for (int nt = 0; nt < 4; ++nt) {
            const int col = colBase + nt * 16;
            #pragma unroll
            for (int r = 0; r < 4; ++r)
                H[(rg + r) * 128 + col] = acc[mt][nt][r];
        }
    }
}

// ---------------- K2: IF scan over t + logits = cnt @ W2^T ----------------
__global__ __launch_bounds__(256) void snn_scan(const float* __restrict__ H,
                                                const float* __restrict__ W2,
                                                float* __restrict__ out) {
    __shared__ float cbuf[2][128];
    __shared__ float w2s[1000];
    const int tid = threadIdx.x;
    const int r = tid >> 7, h = tid & 127;
    const size_t b = (size_t)blockIdx.x * 2 + r;
    for (int i = tid; i < 1000; i += 256) w2s[i] = W2[i];

    float hv[32];
    #pragma unroll
    for (int t = 0; t < 32; ++t) hv[t] = H[((size_t)t * NB + b) * 128 + h];

    float v = 0.f, cnt = 0.f;
    #pragma unroll
    for (int t = 0; t < 32; ++t) {
        v += hv[t];
        float s = (v - 1.0f > 0.0f) ? 1.0f : 0.0f;      // exact reference semantics
        v -= s;
        cnt += s;
    }
    cbuf[r][h] = cnt;
    __syncthreads();
    if (tid < 20) {
        const int rr = tid / 10, o = tid % 10;
        float s = 0.f;
        for (int hh = 0; hh < 100; ++hh) s += cbuf[rr][hh] * w2s[o * 100 + hh];
        out[((size_t)blockIdx.x * 2 + rr) * 10 + o] = s;
    }
}

extern "C" void kernel_launch(void* const* d_in, const int* in_sizes, int n_in,
                              void* d_out, int out_size, void* d_ws, size_t ws_size,
                              hipStream_t stream) {
    const float* x     = (const float*)d_in[0];   // [8192,784]
    const float* noise = (const float*)d_in[1];   // [32,8192,784]
    const float* W1    = (const float*)d_in[2];   // [100,784]
    const float* W2    = (const float*)d_in[3];   // [10,100]
    float* out = (float*)d_out;                   // [8192,10]

    unsigned short* wf = (unsigned short*)d_ws;                    // 409.6 KB W1 frags
    float* H = (float*)((char*)d_ws + (1u << 20));                 // 128 MB H buffer

    prep_w1<<<50, 256, 0, stream>>>(W1, wf);
    snn_gemm<<<2048, 256, 0, stream>>>(x, noise, wf, H);
    snn_scan<<<4096, 256, 0, stream>>>(H, W2, out);
}